// Round 3
// baseline (165.365 us; speedup 1.0000x reference)
//
#include <hip/hip_runtime.h>

// Luong attention, flash-style, f16 MFMA path, software-pipelined.
// enc [B,Te,D] f32, dec [B,Td,D] f32 -> out [B,Td,2D] f32 (concat(dec, context))
// Prepass (fused): enc -> encK f16 (row-major, chunk-swizzled within 64-d group)
//                  enc -> encVt f16 (tiled [b][e/32][d][32], chunk-swizzled)
// Main: 512 thr = 2 e-groups x 4 t-waves; KBLK=32, double-buffered LDS,
//       pipelined: [PV(it) || QK(it+1)] -> bar -> STAGE(it+2) -> softmax(it+1) -> bar

#define B_   8
#define TE   2048
#define TD   2048
#define D_   256
#define NIT  32   // (TE/2)/32 k-tiles per e-group

typedef _Float16 f16x8 __attribute__((ext_vector_type(8)));
typedef float f32x4 __attribute__((ext_vector_type(4)));

__device__ __forceinline__ unsigned pk2(float a, float b) {
  unsigned short ua = __builtin_bit_cast(unsigned short, (_Float16)a);
  unsigned short ub = __builtin_bit_cast(unsigned short, (_Float16)b);
  return (unsigned)ua | ((unsigned)ub << 16);
}

#define GLOAD16(gsrc, ldst)                                                  \
  __builtin_amdgcn_global_load_lds(                                          \
      (const __attribute__((address_space(1))) unsigned int*)(const void*)(gsrc), \
      (__attribute__((address_space(3))) unsigned int*)(void*)(ldst), 16, 0, 0)

// ---- fused prepass: one 64e x 64d f32 tile -> encK chunk + encVt chunk ----
// encK[b][e][x'*8..]: chunk x' holds source chunk (x'&24)|((x'&7)^(e&7))
// encVt[b][ct][d][e32]: slot e32=y*8+j holds enc[ct*32 + (y^((d>>1)&3))*8 + j][d]
__global__ __launch_bounds__(256) void prep_fused(const float* __restrict__ enc,
                                                  _Float16* __restrict__ encK,
                                                  _Float16* __restrict__ encVt) {
  __shared__ float tile[64][65];
  int bid = blockIdx.x;                 // 8 b * 32 et * 4 dt = 1024
  int b = bid >> 7, r = bid & 127;
  int et = r >> 2, dt = r & 3;
  int e0 = et * 64, d0 = dt * 64;
  int tx = threadIdx.x & 63, ty = threadIdx.x >> 6;
  const float* src = enc + ((size_t)b * TE + e0) * D_ + d0;
#pragma unroll
  for (int i = 0; i < 16; ++i)
    tile[i * 4 + ty][tx] = src[(size_t)(i * 4 + ty) * D_ + tx];
  __syncthreads();

  // encK chunk (64 rows x 8 x 16B)
  _Float16* kout = encK + ((size_t)b * TE + e0) * D_ + d0;
#pragma unroll
  for (int i = 0; i < 2; ++i) {
    int ci = i * 256 + threadIdx.x;     // 0..511
    int e = ci >> 3, xl = ci & 7;
    int xs = xl ^ (e & 7);
    const float* s8 = &tile[e][xs * 8];
    f16x8 h;
#pragma unroll
    for (int j = 0; j < 8; ++j) h[j] = (_Float16)s8[j];
    *(f16x8*)(kout + (size_t)e * D_ + xl * 8) = h;
  }
  // encVt chunk (2 ct x 64 d x 32 e16)
#pragma unroll
  for (int i = 0; i < 2; ++i) {
    int u = i * 256 + threadIdx.x;      // 0..511
    int y = u & 3, d_loc = (u >> 2) & 63, ctl = u >> 8;
    int s = (d_loc >> 1) & 3;
    int ebase = ctl * 32 + ((y ^ s) << 3);
    f16x8 h;
#pragma unroll
    for (int j = 0; j < 8; ++j) h[j] = (_Float16)tile[ebase + j][d_loc];
    size_t o = (((size_t)b * 64 + et * 2 + ctl) * 256 + d0 + d_loc) * 32 + y * 8;
    *(f16x8*)(encVt + o) = h;
  }
}

__global__ __launch_bounds__(512, 2) void luong_main(
    const _Float16* __restrict__ encK,   // [B][TE][256] swizzled
    const _Float16* __restrict__ encVt,  // [B][64][256][32] tiled/swizzled
    const float* __restrict__ dec,
    float* __restrict__ out) {
  extern __shared__ char lds[];
  const int tid = threadIdx.x;
  const int lane = tid & 63, wave = tid >> 6;
  const int wr = wave >> 2, wc = wave & 3;   // e-group, t-group
  const int g = lane >> 4, c = lane & 15;

  int bidl = (blockIdx.x & 7) * 32 + (blockIdx.x >> 3);  // XCD k <- batch k
  const int b = bidl >> 5;
  const int q0 = (bidl & 31) * 64;
  const int t = q0 + wc * 16 + c;

  const float* decB = dec + (size_t)b * TD * D_;
  float* outB = out + (size_t)b * TD * (2 * D_);

  // ---- Q fragments f16 hi/lo ----
  f16x8 qh[8], ql[8];
  {
    const float* qrow = decB + (size_t)t * D_;
#pragma unroll
    for (int dc = 0; dc < 8; ++dc) {
      float4 v0 = *(const float4*)(qrow + dc * 32 + 8 * g);
      float4 v1 = *(const float4*)(qrow + dc * 32 + 8 * g + 4);
      float f[8] = {v0.x, v0.y, v0.z, v0.w, v1.x, v1.y, v1.z, v1.w};
      f16x8 H, L;
#pragma unroll
      for (int j = 0; j < 8; ++j) {
        _Float16 h = (_Float16)f[j];
        H[j] = h;
        L[j] = (_Float16)(f[j] - (float)h);
      }
      qh[dc] = H; ql[dc] = L;
    }
  }

  const _Float16* kbase = encK + ((size_t)b * TE + wr * 1024) * D_;
  const _Float16* vbase = encVt + ((size_t)b * 64 + wr * 32) * 8192;

  auto STAGE = [&](int buf, int it) {
    char* Kd = lds + (size_t)(buf * 2 + wr) * 32768;
    char* Vd = Kd + 16384;
    const _Float16* ks = kbase + (size_t)it * 8192;
    const _Float16* vs = vbase + (size_t)it * 8192;
#pragma unroll
    for (int q = 0; q < 4; ++q) {
      int chunk = wc * 256 + q * 64 + lane;
      GLOAD16(ks + (size_t)chunk * 8, Kd + wc * 4096 + q * 1024);
      GLOAD16(vs + (size_t)chunk * 8, Vd + wc * 4096 + q * 1024);
    }
  };

  float m_run = -INFINITY, l_run = 0.f;
  f32x4 ctx[16];
#pragma unroll
  for (int i = 0; i < 16; ++i) ctx[i] = (f32x4){0.f, 0.f, 0.f, 0.f};

  f32x4 sA, sB;
  f16x8 bfrag;

  auto QK = [&](const char* Kb, f32x4& oA, f32x4& oB) {
    oA = (f32x4){0.f, 0.f, 0.f, 0.f};
    oB = (f32x4){0.f, 0.f, 0.f, 0.f};
    const int el0 = c, el1 = 16 + c;
#pragma unroll
    for (int dc = 0; dc < 8; ++dc) {
      int x = dc * 4 + g;
      int xsw = (x & 24) | ((x ^ el0) & 7);   // el1&7 == el0&7
      f16x8 k0 = *(const f16x8*)(Kb + el0 * 512 + (xsw << 4));
      f16x8 k1 = *(const f16x8*)(Kb + el1 * 512 + (xsw << 4));
      oA = __builtin_amdgcn_mfma_f32_16x16x32_f16(k0, qh[dc], oA, 0, 0, 0);
      oA = __builtin_amdgcn_mfma_f32_16x16x32_f16(k0, ql[dc], oA, 0, 0, 0);
      oB = __builtin_amdgcn_mfma_f32_16x16x32_f16(k1, qh[dc], oB, 0, 0, 0);
      oB = __builtin_amdgcn_mfma_f32_16x16x32_f16(k1, ql[dc], oB, 0, 0, 0);
    }
  };

  auto PV = [&](const char* Vb) {
#pragma unroll
    for (int dt = 0; dt < 16; ++dt) {
      int row = dt * 16 + c;
      f16x8 af = *(const f16x8*)(Vb + row * 64 + ((g ^ ((row >> 1) & 3)) << 4));
      ctx[dt] = __builtin_amdgcn_mfma_f32_16x16x32_f16(af, bfrag, ctx[dt], 0, 0, 0);
    }
  };

  auto SOFTMAX = [&]() {
    float vmax = fmaxf(fmaxf(fmaxf(sA[0], sA[1]), fmaxf(sA[2], sA[3])),
                       fmaxf(fmaxf(sB[0], sB[1]), fmaxf(sB[2], sB[3])));
    vmax = fmaxf(vmax, __shfl_xor(vmax, 16, 64));
    vmax = fmaxf(vmax, __shfl_xor(vmax, 32, 64));
    // T13 defer-max: skip rescale when tile max doesn't exceed m_run+8
    if (!__all(vmax <= m_run + 8.0f)) {
      float m_new = fmaxf(m_run, vmax);
      float alpha = __expf(m_run - m_new);
      l_run *= alpha;
#pragma unroll
      for (int i = 0; i < 16; ++i) ctx[i] *= alpha;
      m_run = m_new;
    }
    float p0 = __expf(sA[0] - m_run), p1 = __expf(sA[1] - m_run);
    float p2 = __expf(sA[2] - m_run), p3 = __expf(sA[3] - m_run);
    float p4 = __expf(sB[0] - m_run), p5 = __expf(sB[1] - m_run);
    float p6 = __expf(sB[2] - m_run), p7 = __expf(sB[3] - m_run);
    float ps = ((p0 + p1) + (p2 + p3)) + ((p4 + p5) + (p6 + p7));
    ps += __shfl_xor(ps, 16, 64);
    ps += __shfl_xor(ps, 32, 64);
    l_run += ps;
    unsigned w00 = pk2(p0, p1), w10 = pk2(p2, p3);
    unsigned w01 = pk2(p4, p5), w11 = pk2(p6, p7);
    int srcA = (2 * (g & 1)) * 16 + c, srcB = srcA + 16;
    int y0 = __shfl((int)w00, srcA, 64), y1 = __shfl((int)w10, srcA, 64);
    int y2 = __shfl((int)w00, srcB, 64), y3 = __shfl((int)w10, srcB, 64);
    int z0 = __shfl((int)w01, srcA, 64), z1 = __shfl((int)w11, srcA, 64);
    int z2 = __shfl((int)w01, srcB, 64), z3 = __shfl((int)w11, srcB, 64);
    int4 bi = (g >> 1) ? make_int4(z0, z1, z2, z3) : make_int4(y0, y1, y2, y3);
    bfrag = __builtin_bit_cast(f16x8, bi);
  };

  // ---- prologue ----
  STAGE(0, 0);
  // dec -> out[:, :256] copy (overlaps first stage)
#pragma unroll
  for (int i = 0; i < 8; ++i) {
    int ci = tid + 512 * i;
    int rr = ci >> 6, d4 = (ci & 63) << 2;
    *(float4*)(outB + (size_t)(q0 + rr) * 512 + d4) =
        *(const float4*)(decB + (size_t)(q0 + rr) * 256 + d4);
  }
  __syncthreads();                       // STAGE(0) landed
  STAGE(1, 1);
  QK(lds + (size_t)wr * 32768, sA, sB);  // tile 0, buf0
  SOFTMAX();                             // -> bfrag(0)
  __syncthreads();                       // STAGE(1) landed

  // ---- pipelined main loop ----
#pragma unroll 2
  for (int it = 0; it < NIT; ++it) {
    const int cur = it & 1;
    const char* bufC = lds + (size_t)(cur * 2 + wr) * 32768;        // tile it
    const char* bufN = lds + (size_t)((cur ^ 1) * 2 + wr) * 32768;  // tile it+1
    f32x4 nA, nB;
    __builtin_amdgcn_s_setprio(1);
    if (it + 1 < NIT) QK(bufN, nA, nB);   // QK(it+1) || PV(it)
    PV(bufC + 16384);
    __builtin_amdgcn_s_setprio(0);
    __syncthreads();                      // all reads of bufC done
    if (it + 2 < NIT) STAGE(cur, it + 2); // overwrite bufC with tile it+2
    if (it + 1 < NIT) {
      sA = nA; sB = nB;
      SOFTMAX();                          // overlaps STAGE flight
      __syncthreads();                    // STAGE(it+2) landed
    }
  }

  // ---- cross-group merge (2 e-groups) ----
  float* mlb = (float*)(lds + 69632);
  if (lane < 16) {
    mlb[((wr * 4 + wc) * 16 + c) * 2 + 0] = m_run;
    mlb[((wr * 4 + wc) * 16 + c) * 2 + 1] = l_run;
  }
  __syncthreads();
  float m_o = mlb[(((1 - wr) * 4 + wc) * 16 + c) * 2 + 0];
  float l_o = mlb[(((1 - wr) * 4 + wc) * 16 + c) * 2 + 1];
  float M = fmaxf(m_run, m_o);
  float fme = __expf(m_run - M);
  float L = l_run * fme + l_o * __expf(m_o - M);
  float invL = 1.0f / L;

  float* Xb = (float*)lds + wc * 4352;   // [256][17] f32 per t-group
  if (wr == 1) {
#pragma unroll
    for (int dt = 0; dt < 16; ++dt)
#pragma unroll
      for (int r = 0; r < 4; ++r) {
        int d = dt * 16 + 4 * g + r;
        Xb[d * 17 + c] = ctx[dt][r] * fme;
      }
  }
  __syncthreads();
  if (wr == 0) {
    float* orow = outB + (size_t)t * 512 + 256;
#pragma unroll
    for (int dt = 0; dt < 16; ++dt) {
      float4 v;
      float vv[4];
#pragma unroll
      for (int r = 0; r < 4; ++r) {
        int d = dt * 16 + 4 * g + r;
        vv[r] = (ctx[dt][r] * fme + Xb[d * 17 + c]) * invL;
      }
      v.x = vv[0]; v.y = vv[1]; v.z = vv[2]; v.w = vv[3];
      *(float4*)(orow + dt * 16 + 4 * g) = v;
    }
  }
}

extern "C" void kernel_launch(void* const* d_in, const int* in_sizes, int n_in,
                              void* d_out, int out_size, void* d_ws, size_t ws_size,
                              hipStream_t stream) {
  const float* enc = (const float*)d_in[0];
  const float* dec = (const float*)d_in[1];
  float* out = (float*)d_out;
  (void)in_sizes; (void)n_in; (void)out_size; (void)ws_size;

  _Float16* encK  = (_Float16*)d_ws;                           // 8 MiB
  _Float16* encVt = (_Float16*)((char*)d_ws + 8388608);        // 8 MiB

  prep_fused<<<1024, 256, 0, stream>>>(enc, encK, encVt);
  luong_main<<<256, 512, 131072, stream>>>(encK, encVt, dec, out);
}

// Round 4
// 157.327 us; speedup vs baseline: 1.0511x; 1.0511x over previous
//
#include <hip/hip_runtime.h>

// Luong attention, flash-style, f16 MFMA path, counted-vmcnt pipeline (T3/T4).
// enc [B,Te,D] f32, dec [B,Td,D] f32 -> out [B,Td,2D] f32 (concat(dec, context))
// Prepass (fused): enc -> encK f16 (row-major, chunk-swizzled within 64-d group)
//                  enc -> encVt f16 (tiled [b][e/32][d][32], chunk-swizzled)
// Main: 512 thr = 2 e-groups x 4 t-waves; KBLK=32, double-buffered LDS.
//   iter it: QK(bufC) -> SM -> PV(bufC) -> lgkm0+bar -> STAGE(it+2->bufC)
//            -> vmcnt(8) [tile it+1 landed, tile it+2 stays in flight] -> bar

#define B_   8
#define TE   2048
#define TD   2048
#define D_   256
#define NIT  32   // (TE/2)/32 k-tiles per e-group

typedef _Float16 f16x8 __attribute__((ext_vector_type(8)));
typedef float f32x4 __attribute__((ext_vector_type(4)));

__device__ __forceinline__ unsigned pk2(float a, float b) {
  unsigned short ua = __builtin_bit_cast(unsigned short, (_Float16)a);
  unsigned short ub = __builtin_bit_cast(unsigned short, (_Float16)b);
  return (unsigned)ua | ((unsigned)ub << 16);
}

#define GLOAD16(gsrc, ldst)                                                  \
  __builtin_amdgcn_global_load_lds(                                          \
      (const __attribute__((address_space(1))) unsigned int*)(const void*)(gsrc), \
      (__attribute__((address_space(3))) unsigned int*)(void*)(ldst), 16, 0, 0)

// ---- fused prepass: one 64e x 64d f32 tile -> encK chunk + encVt chunk ----
__global__ __launch_bounds__(256) void prep_fused(const float* __restrict__ enc,
                                                  _Float16* __restrict__ encK,
                                                  _Float16* __restrict__ encVt) {
  __shared__ float tile[64][65];
  int bid = blockIdx.x;                 // 8 b * 32 et * 4 dt = 1024
  int b = bid >> 7, r = bid & 127;
  int et = r >> 2, dt = r & 3;
  int e0 = et * 64, d0 = dt * 64;
  int tx = threadIdx.x & 63, ty = threadIdx.x >> 6;
  const float* src = enc + ((size_t)b * TE + e0) * D_ + d0;
#pragma unroll
  for (int i = 0; i < 16; ++i)
    tile[i * 4 + ty][tx] = src[(size_t)(i * 4 + ty) * D_ + tx];
  __syncthreads();

  // encK chunk (64 rows x 8 x 16B), chunk xl holds source chunk xl^(e&7)
  _Float16* kout = encK + ((size_t)b * TE + e0) * D_ + d0;
#pragma unroll
  for (int i = 0; i < 2; ++i) {
    int ci = i * 256 + threadIdx.x;     // 0..511
    int e = ci >> 3, xl = ci & 7;
    int xs = xl ^ (e & 7);
    const float* s8 = &tile[e][xs * 8];
    f16x8 h;
#pragma unroll
    for (int j = 0; j < 8; ++j) h[j] = (_Float16)s8[j];
    *(f16x8*)(kout + (size_t)e * D_ + xl * 8) = h;
  }
  // encVt chunk: slot y holds source e-chunk y^((d>>1)&3)
#pragma unroll
  for (int i = 0; i < 2; ++i) {
    int u = i * 256 + threadIdx.x;      // 0..511
    int y = u & 3, d_loc = (u >> 2) & 63, ctl = u >> 8;
    int s = (d_loc >> 1) & 3;
    int ebase = ctl * 32 + ((y ^ s) << 3);
    f16x8 h;
#pragma unroll
    for (int j = 0; j < 8; ++j) h[j] = (_Float16)tile[ebase + j][d_loc];
    size_t o = (((size_t)b * 64 + et * 2 + ctl) * 256 + d0 + d_loc) * 32 + y * 8;
    *(f16x8*)(encVt + o) = h;
  }
}

__global__ __launch_bounds__(512, 2) void luong_main(
    const _Float16* __restrict__ encK,   // [B][TE][256] swizzled
    const _Float16* __restrict__ encVt,  // [B][64][256][32] tiled/swizzled
    const float* __restrict__ dec,
    float* __restrict__ out) {
  extern __shared__ char lds[];
  const int tid = threadIdx.x;
  const int lane = tid & 63, wave = tid >> 6;
  const int wr = wave >> 2, wc = wave & 3;   // e-group, t-group
  const int g = lane >> 4, c = lane & 15;

  int bidl = (blockIdx.x & 7) * 32 + (blockIdx.x >> 3);  // XCD k <- batch k
  const int b = bidl >> 5;
  const int q0 = (bidl & 31) * 64;
  const int t = q0 + wc * 16 + c;

  const float* decB = dec + (size_t)b * TD * D_;
  float* outB = out + (size_t)b * TD * (2 * D_);

  const _Float16* kbase = encK + ((size_t)b * TE + wr * 1024) * D_;
  const _Float16* vbase = encVt + ((size_t)b * 64 + wr * 32) * 8192;

  auto STAGE = [&](int buf, int it) {
    char* Kd = lds + (size_t)(buf * 2 + wr) * 32768;
    char* Vd = Kd + 16384;
    const _Float16* ks = kbase + (size_t)it * 8192;
    const _Float16* vs = vbase + (size_t)it * 8192;
#pragma unroll
    for (int q = 0; q < 4; ++q) {
      int chunk = wc * 256 + q * 64 + lane;
      GLOAD16(ks + (size_t)chunk * 8, Kd + wc * 4096 + q * 1024);
      GLOAD16(vs + (size_t)chunk * 8, Vd + wc * 4096 + q * 1024);
    }
  };

  // ---- prologue staging first: maximize load-issue lead ----
  STAGE(0, 0);
  STAGE(1, 1);

  // dec -> out[:, :256] copy (overlaps staging flight)
#pragma unroll
  for (int i = 0; i < 8; ++i) {
    int ci = tid + 512 * i;
    int rr = ci >> 6, d4 = (ci & 63) << 2;
    *(float4*)(outB + (size_t)(q0 + rr) * 512 + d4) =
        *(const float4*)(decB + (size_t)(q0 + rr) * 256 + d4);
  }

  // ---- Q fragments f16 hi/lo ----
  f16x8 qh[8], ql[8];
  {
    const float* qrow = decB + (size_t)t * D_;
#pragma unroll
    for (int dc = 0; dc < 8; ++dc) {
      float4 v0 = *(const float4*)(qrow + dc * 32 + 8 * g);
      float4 v1 = *(const float4*)(qrow + dc * 32 + 8 * g + 4);
      float f[8] = {v0.x, v0.y, v0.z, v0.w, v1.x, v1.y, v1.z, v1.w};
      f16x8 H, L;
#pragma unroll
      for (int j = 0; j < 8; ++j) {
        _Float16 h = (_Float16)f[j];
        H[j] = h;
        L[j] = (_Float16)(f[j] - (float)h);
      }
      qh[dc] = H; ql[dc] = L;
    }
  }

  float m_run = -INFINITY, l_run = 0.f;
  f32x4 ctx[16];
#pragma unroll
  for (int i = 0; i < 16; ++i) ctx[i] = (f32x4){0.f, 0.f, 0.f, 0.f};

  f32x4 sA, sB;
  f16x8 bfrag;

  auto QK = [&](const char* Kb) {
    sA = (f32x4){0.f, 0.f, 0.f, 0.f};
    sB = (f32x4){0.f, 0.f, 0.f, 0.f};
    const int el0 = c, el1 = 16 + c;
#pragma unroll
    for (int dc = 0; dc < 8; ++dc) {
      int x = dc * 4 + g;
      int xsw = (x & 24) | ((x ^ el0) & 7);   // el1&7 == el0&7
      f16x8 k0 = *(const f16x8*)(Kb + el0 * 512 + (xsw << 4));
      f16x8 k1 = *(const f16x8*)(Kb + el1 * 512 + (xsw << 4));
      sA = __builtin_amdgcn_mfma_f32_16x16x32_f16(k0, qh[dc], sA, 0, 0, 0);
      sA = __builtin_amdgcn_mfma_f32_16x16x32_f16(k0, ql[dc], sA, 0, 0, 0);
      sB = __builtin_amdgcn_mfma_f32_16x16x32_f16(k1, qh[dc], sB, 0, 0, 0);
      sB = __builtin_amdgcn_mfma_f32_16x16x32_f16(k1, ql[dc], sB, 0, 0, 0);
    }
  };

  auto PV = [&](const char* Vb) {
#pragma unroll
    for (int dt = 0; dt < 16; ++dt) {
      int row = dt * 16 + c;
      f16x8 af = *(const f16x8*)(Vb + row * 64 + ((g ^ ((row >> 1) & 3)) << 4));
      ctx[dt] = __builtin_amdgcn_mfma_f32_16x16x32_f16(af, bfrag, ctx[dt], 0, 0, 0);
    }
  };

  auto SOFTMAX = [&]() {
    float vmax = fmaxf(fmaxf(fmaxf(sA[0], sA[1]), fmaxf(sA[2], sA[3])),
                       fmaxf(fmaxf(sB[0], sB[1]), fmaxf(sB[2], sB[3])));
    vmax = fmaxf(vmax, __shfl_xor(vmax, 16, 64));
    vmax = fmaxf(vmax, __shfl_xor(vmax, 32, 64));
    // T13 defer-max: skip rescale when tile max doesn't exceed m_run+8
    if (!__all(vmax <= m_run + 8.0f)) {
      float m_new = fmaxf(m_run, vmax);
      float alpha = __expf(m_run - m_new);
      l_run *= alpha;
#pragma unroll
      for (int i = 0; i < 16; ++i) ctx[i] *= alpha;
      m_run = m_new;
    }
    float p0 = __expf(sA[0] - m_run), p1 = __expf(sA[1] - m_run);
    float p2 = __expf(sA[2] - m_run), p3 = __expf(sA[3] - m_run);
    float p4 = __expf(sB[0] - m_run), p5 = __expf(sB[1] - m_run);
    float p6 = __expf(sB[2] - m_run), p7 = __expf(sB[3] - m_run);
    float ps = ((p0 + p1) + (p2 + p3)) + ((p4 + p5) + (p6 + p7));
    ps += __shfl_xor(ps, 16, 64);
    ps += __shfl_xor(ps, 32, 64);
    l_run += ps;
    unsigned w00 = pk2(p0, p1), w10 = pk2(p2, p3);
    unsigned w01 = pk2(p4, p5), w11 = pk2(p6, p7);
    int srcA = (2 * (g & 1)) * 16 + c, srcB = srcA + 16;
    int y0 = __shfl((int)w00, srcA, 64), y1 = __shfl((int)w10, srcA, 64);
    int y2 = __shfl((int)w00, srcB, 64), y3 = __shfl((int)w10, srcB, 64);
    int z0 = __shfl((int)w01, srcA, 64), z1 = __shfl((int)w11, srcA, 64);
    int z2 = __shfl((int)w01, srcB, 64), z3 = __shfl((int)w11, srcB, 64);
    int4 bi = (g >> 1) ? make_int4(z0, z1, z2, z3) : make_int4(y0, y1, y2, y3);
    bfrag = __builtin_bit_cast(f16x8, bi);
  };

  // tile 0 landed (tile 1 may stay in flight)
  asm volatile("s_waitcnt vmcnt(8)" ::: "memory");
  __builtin_amdgcn_sched_barrier(0);
  __builtin_amdgcn_s_barrier();
  __builtin_amdgcn_sched_barrier(0);

  // ---- main loop: counted-vmcnt double-buffer pipeline ----
#pragma unroll 2
  for (int it = 0; it < NIT; ++it) {
    const int cur = it & 1;
    const char* bufC = lds + (size_t)(cur * 2 + wr) * 32768;   // tile it

    __builtin_amdgcn_s_setprio(1);
    QK(bufC);
    __builtin_amdgcn_s_setprio(0);
    SOFTMAX();
    __builtin_amdgcn_s_setprio(1);
    PV(bufC + 16384);
    __builtin_amdgcn_s_setprio(0);

    // barrier 1: all waves done reading bufC (drain own ds_reads first)
    asm volatile("s_waitcnt lgkmcnt(0)" ::: "memory");
    __builtin_amdgcn_sched_barrier(0);
    __builtin_amdgcn_s_barrier();
    __builtin_amdgcn_sched_barrier(0);

    if (it + 2 < NIT) {
      STAGE(cur, it + 2);                       // overwrite bufC with tile it+2
      // wait tile it+1 (issued one full iteration ago); it+2 stays in flight
      asm volatile("s_waitcnt vmcnt(8)" ::: "memory");
    } else {
      asm volatile("s_waitcnt vmcnt(0)" ::: "memory");
    }
    __builtin_amdgcn_sched_barrier(0);
    __builtin_amdgcn_s_barrier();               // barrier 2: next tile ready
    __builtin_amdgcn_sched_barrier(0);
  }

  // ---- cross-group merge (2 e-groups); loop tail barrier ordered all waves ----
  float* mlb = (float*)(lds + 130048);   // last 1KB of buf(1,wr=1) region
  if (lane < 16) {
    mlb[((wr * 4 + wc) * 16 + c) * 2 + 0] = m_run;
    mlb[((wr * 4 + wc) * 16 + c) * 2 + 1] = l_run;
  }
  __syncthreads();
  float m_o = mlb[(((1 - wr) * 4 + wc) * 16 + c) * 2 + 0];
  float l_o = mlb[(((1 - wr) * 4 + wc) * 16 + c) * 2 + 1];
  float M = fmaxf(m_run, m_o);
  float fme = __expf(m_run - M);
  float L = l_run * fme + l_o * __expf(m_o - M);
  float invL = 1.0f / L;

  float* Xb = (float*)lds + wc * 4352;   // [256][17] f32 per t-group
  if (wr == 1) {
#pragma unroll
    for (int dt = 0; dt < 16; ++dt)
#pragma unroll
      for (int r = 0; r < 4; ++r) {
        int d = dt * 16 + 4 * g + r;
        Xb[d * 17 + c] = ctx[dt][r] * fme;
      }
  }
  __syncthreads();
  if (wr == 0) {
    float* orow = outB + (size_t)t * 512 + 256;
#pragma unroll
    for (int dt = 0; dt < 16; ++dt) {
      float4 v;
      float vv[4];
#pragma unroll
      for (int r = 0; r < 4; ++r) {
        int d = dt * 16 + 4 * g + r;
        vv[r] = (ctx[dt][r] * fme + Xb[d * 17 + c]) * invL;
      }
      v.x = vv[0]; v.y = vv[1]; v.z = vv[2]; v.w = vv[3];
      *(float4*)(orow + dt * 16 + 4 * g) = v;
    }
  }
}

extern "C" void kernel_launch(void* const* d_in, const int* in_sizes, int n_in,
                              void* d_out, int out_size, void* d_ws, size_t ws_size,
                              hipStream_t stream) {
  const float* enc = (const float*)d_in[0];
  const float* dec = (const float*)d_in[1];
  float* out = (float*)d_out;
  (void)in_sizes; (void)n_in; (void)out_size; (void)ws_size;

  _Float16* encK  = (_Float16*)d_ws;                           // 8 MiB
  _Float16* encVt = (_Float16*)((char*)d_ws + 8388608);        // 8 MiB

  prep_fused<<<1024, 256, 0, stream>>>(enc, encK, encVt);
  luong_main<<<256, 512, 131072, stream>>>(encK, encVt, dec, out);
}